// Round 12
// baseline (336.800 us; speedup 1.0000x reference)
//
#include <hip/hip_runtime.h>

#define D 128
#define RPB 32          // rows per bucket
#define SHIFT 5         // log2(RPB)
#define PB 256          // partition blocks
#define CAP 1536        // max edges per bucket chunk (avg 512)

typedef __attribute__((ext_vector_type(8))) short short8;
typedef __attribute__((ext_vector_type(4))) float f32x4;
typedef __attribute__((ext_vector_type(2))) float f32x2;

// ---- bf16 pack helpers (round-to-nearest-even)
__device__ inline unsigned bfr(float f) {
  unsigned u = __float_as_uint(f);
  return (u + 0x7fffu + ((u >> 16) & 1u)) >> 16;
}
__device__ inline unsigned pack2(float lo, float hi) {
  return bfr(lo) | (bfr(hi) << 16);
}
__device__ inline float unpk_lo(unsigned v) { return __uint_as_float(v << 16); }
__device__ inline float unpk_hi(unsigned v) { return __uint_as_float(v & 0xffff0000u); }

// ---------------- hist: per-chunk LDS histogram of dst buckets (role A);
// zeros ssum; W1 fp32 -> bf16 transposed Wtg (role B, 64 blocks)
__global__ __launch_bounds__(256) void k_hist(const int* __restrict__ dst,
                                              int* __restrict__ phT,
                                              float* __restrict__ ssum,
                                              const float* __restrict__ W,
                                              unsigned short* __restrict__ Wtg,
                                              int N, int E, int NBKT, int ECH) {
  __shared__ int hist[4096];
  int b = blockIdx.x, t = threadIdx.x;
  if (b >= PB) {
    int i = (b - PB) * 256 + t;
    if (i < 128 * 128) {
      int k = i >> 7, n = i & 127;
      Wtg[n * 128 + k] = (unsigned short)bfr(W[k * 128 + n]);
    }
    return;
  }
  for (int k = t; k < NBKT; k += 256) hist[k] = 0;
  for (int i = b * 256 + t; i < N; i += PB * 256) ssum[i] = 0.f;
  __syncthreads();
  int st = b * ECH, en = min(E, st + ECH);
  for (int i = st + t; i < en; i += 256) atomicAdd(&hist[dst[i] >> SHIFT], 1);
  __syncthreads();
  for (int k = t; k < NBKT; k += 256) phT[k * PB + b] = hist[k];
}

// ---------------- mid: per-4096-chunk sums of phT
__global__ __launch_bounds__(256) void k_mid(const int* __restrict__ phT,
                                             int* __restrict__ bsumP, int T) {
  int t = threadIdx.x;
  int base = blockIdx.x * 4096 + t * 16;
  int s = 0;
  #pragma unroll
  for (int j = 0; j < 16; ++j) {
    int idx = base + j;
    if (idx < T) s += phT[idx];
  }
  __shared__ int red[256];
  red[t] = s;
  __syncthreads();
  for (int off = 128; off > 0; off >>= 1) {
    if (t < off) red[t] += red[t + off];
    __syncthreads();
  }
  if (t == 0) bsumP[blockIdx.x] = red[0];
}

// ---------------- scanC: in-place exclusive scan of phT (bucket-major base table)
__global__ __launch_bounds__(256) void k_scanC(int* __restrict__ phT,
                                               const int* __restrict__ bsumP,
                                               int nsc, int T) {
  int t = threadIdx.x;
  __shared__ int sc2[256];
  sc2[t] = (t < nsc) ? bsumP[t] : 0;
  __syncthreads();
  #pragma unroll
  for (int off = 1; off < 256; off <<= 1) {
    int x = (t >= off) ? sc2[t - off] : 0;
    __syncthreads();
    sc2[t] += x;
    __syncthreads();
  }
  int bbase = (blockIdx.x == 0) ? 0 : sc2[blockIdx.x - 1];

  int base = blockIdx.x * 4096 + t * 16;
  int v[16];
  int s = 0;
  #pragma unroll
  for (int j = 0; j < 16; ++j) {
    int idx = base + j;
    v[j] = (idx < T) ? phT[idx] : 0;
    s += v[j];
  }
  __shared__ int sc[256];
  sc[t] = s;
  __syncthreads();
  for (int off = 1; off < 256; off <<= 1) {
    int x = (t >= off) ? sc[t - off] : 0;
    __syncthreads();
    sc[t] += x;
    __syncthreads();
  }
  int p = bbase + sc[t] - s;
  #pragma unroll
  for (int j = 0; j < 16; ++j) {
    int idx = base + j;
    if (idx < T) {
      phT[idx] = p;
      p += v[j];
    }
  }
}

// ---------------- FUSED: pscat (role A, PB blocks) || MFMA gemm h = x@W1 (role B)
// h stored as fp8 e4m3, 128 B/row (halves gather bytes in k_bagg).
__global__ __launch_bounds__(256) void k_scat_gemm(
    const int* __restrict__ src, const int* __restrict__ dst,
    const int* __restrict__ phT, int* __restrict__ eb,
    const float* __restrict__ x, const unsigned short* __restrict__ Wtg,
    unsigned short* __restrict__ hu8, int M, int E, int NBKT, int ECH) {
  __shared__ int shm[4352];  // 17408 B shared by both roles
  int b = blockIdx.x, t = threadIdx.x;

  if (b < PB) {
    // ---- pscat role: scatter edges into bucket-grouped eb via LDS cursors
    int* cur = shm;
    for (int k = t; k < NBKT; k += 256) cur[k] = phT[k * PB + b];
    __syncthreads();
    int st = b * ECH, en = min(E, st + ECH);
    for (int i = st + t * 4; i < en; i += 1024) {
      if (i + 3 < en) {
        int4 s4 = *(const int4*)(src + i);
        int4 d4 = *(const int4*)(dst + i);
        int p0 = atomicAdd(&cur[d4.x >> SHIFT], 1);
        int p1 = atomicAdd(&cur[d4.y >> SHIFT], 1);
        int p2 = atomicAdd(&cur[d4.z >> SHIFT], 1);
        int p3 = atomicAdd(&cur[d4.w >> SHIFT], 1);
        eb[p0] = s4.x | ((d4.x & (RPB - 1)) << 26);
        eb[p1] = s4.y | ((d4.y & (RPB - 1)) << 26);
        eb[p2] = s4.z | ((d4.z & (RPB - 1)) << 26);
        eb[p3] = s4.w | ((d4.w & (RPB - 1)) << 26);
      } else {
        for (int j = i; j < en; ++j) {
          int d = dst[j], s = src[j];
          int pos = atomicAdd(&cur[d >> SHIFT], 1);
          eb[pos] = s | ((d & (RPB - 1)) << 26);
        }
      }
    }
    return;
  }

  // ---- MFMA gemm role
  int row0 = (b - PB) * 64;
  if (row0 >= M) return;
  unsigned short* xs = (unsigned short*)shm;  // [64][136]

  for (int i = t; i < 2048; i += 256) {
    int r = i >> 5;
    int rg = row0 + r;
    int rc = rg < M ? rg : M - 1;
    float4 v = ((const float4*)x)[(size_t)rc * 32 + (i & 31)];
    *(uint2*)&xs[r * 136 + (i & 31) * 4] = make_uint2(pack2(v.x, v.y), pack2(v.z, v.w));
  }
  __syncthreads();

  int lane = t & 63;
  int wid = t >> 6;
  int l15 = lane & 15;
  int quad = lane >> 4;
  int mloc = wid * 16 + l15;

  f32x4 acc[8];
  #pragma unroll
  for (int ct = 0; ct < 8; ++ct) acc[ct] = (f32x4){0.f, 0.f, 0.f, 0.f};

  #pragma unroll
  for (int k0 = 0; k0 < 128; k0 += 32) {
    short8 af = *(const short8*)&xs[mloc * 136 + k0 + quad * 8];
    #pragma unroll
    for (int ct = 0; ct < 8; ++ct) {
      short8 bf = *(const short8*)(Wtg + (ct * 16 + l15) * 128 + k0 + quad * 8);
      acc[ct] = __builtin_amdgcn_mfma_f32_16x16x32_bf16(af, bf, acc[ct], 0, 0, 0);
    }
  }

  int rowbase = row0 + wid * 16 + quad * 4;
  #pragma unroll
  for (int ct = 0; ct < 8; ++ct) {
    #pragma unroll
    for (int r = 0; r < 4; ++r) {
      float v = acc[ct][r];
      float vp = __shfl_xor(v, 1, 64);
      int row = rowbase + r;
      if (!(lane & 1) && row < M) {
        int pk = __builtin_amdgcn_cvt_pk_fp8_f32(v, vp, 0, false);
        hu8[(size_t)row * 64 + ct * 8 + (l15 >> 1)] = (unsigned short)(pk & 0xffff);
      }
    }
  }
}

// ---------------- rowdeg: per-bucket LDS count of local rows -> dinv
__global__ __launch_bounds__(256) void k_rowdeg(const int* __restrict__ eb,
                                                const int* __restrict__ phT,
                                                float* __restrict__ dinv,
                                                int N, int E, int NBKT) {
  __shared__ int cnt[RPB];
  int bkt = blockIdx.x, t = threadIdx.x;
  if (t < RPB) cnt[t] = 0;
  __syncthreads();
  int lo = phT[bkt * PB];
  int hi = (bkt + 1 < NBKT) ? phT[(bkt + 1) * PB] : E;
  for (int i = lo + t; i < hi; i += 256)
    atomicAdd(&cnt[(unsigned)eb[i] >> 26], 1);
  __syncthreads();
  if (t < RPB) {
    int r = bkt * RPB + t;
    if (r < N) dinv[r] = rsqrtf((float)cnt[t] + 1.0f);
  }
}

// ---------------- bucketed aggregate: LDS counting-sort by row, register CSR gather (fp8 h)
__global__ __launch_bounds__(256) void k_bagg(
    const unsigned short* __restrict__ hu8, const int* __restrict__ eb,
    const int* __restrict__ phT, const float* __restrict__ dinv,
    float* __restrict__ ssum, const float* __restrict__ b1,
    unsigned* __restrict__ a1u, int N, int E, int NBKT) {
  __shared__ int raw[CAP];
  __shared__ int srt[CAP];
  __shared__ int rh[RPB + 1];
  __shared__ int rcur[RPB];
  int bkt = blockIdx.x, t = threadIdx.x;
  int lane = t & 63, wid = t >> 6;
  int lo = phT[bkt * PB];
  int hi = (bkt + 1 < NBKT) ? phT[(bkt + 1) * PB] : E;

  float ax[8], ay[8];
  #pragma unroll
  for (int k = 0; k < 8; ++k) { ax[k] = 0.f; ay[k] = 0.f; }

  for (int clo = lo; clo < hi; clo += CAP) {
    int cnt = min(CAP, hi - clo);
    if (t <= RPB) rh[t] = 0;
    __syncthreads();
    for (int i = t; i < cnt; i += 256) {
      int v = eb[clo + i];
      raw[i] = v;
      atomicAdd(&rh[((unsigned)v >> 26) + 1], 1);
    }
    __syncthreads();
    if (t < 32) {
      int x = rh[t + 1];
      #pragma unroll
      for (int o = 1; o < 32; o <<= 1) {
        int y = __shfl_up(x, o, 64);
        if (t >= o) x += y;
      }
      rh[t + 1] = x;
    }
    __syncthreads();
    if (t < RPB) rcur[t] = rh[t];
    __syncthreads();
    for (int i = t; i < cnt; i += 256) {
      int v = raw[i];
      int r = (unsigned)v >> 26;
      int pos = atomicAdd(&rcur[r], 1);
      srt[pos] = v & 0x3FFFFFF;
    }
    __syncthreads();

    #pragma unroll
    for (int k = 0; k < 8; ++k) {
      int rl = wid + k * 4;
      int beg = rh[rl], end = rh[rl + 1];
      int rg = bkt * RPB + rl;
      float di = (rg < N) ? dinv[rg] : 0.f;
      int j = beg;
      for (; j + 8 <= end; j += 8) {
        int s0 = srt[j], s1 = srt[j + 1], s2 = srt[j + 2], s3 = srt[j + 3];
        int s4 = srt[j + 4], s5 = srt[j + 5], s6 = srt[j + 6], s7 = srt[j + 7];
        float e0 = dinv[s0], e1 = dinv[s1], e2 = dinv[s2], e3 = dinv[s3];
        float e4 = dinv[s4], e5 = dinv[s5], e6 = dinv[s6], e7 = dinv[s7];
        unsigned v0 = hu8[(size_t)s0 * 64 + lane];
        unsigned v1 = hu8[(size_t)s1 * 64 + lane];
        unsigned v2 = hu8[(size_t)s2 * 64 + lane];
        unsigned v3 = hu8[(size_t)s3 * 64 + lane];
        unsigned v4 = hu8[(size_t)s4 * 64 + lane];
        unsigned v5 = hu8[(size_t)s5 * 64 + lane];
        unsigned v6 = hu8[(size_t)s6 * 64 + lane];
        unsigned v7 = hu8[(size_t)s7 * 64 + lane];
        if (lane == 0) {
          unsafeAtomicAdd(&ssum[s0], di);
          unsafeAtomicAdd(&ssum[s1], di);
          unsafeAtomicAdd(&ssum[s2], di);
          unsafeAtomicAdd(&ssum[s3], di);
          unsafeAtomicAdd(&ssum[s4], di);
          unsafeAtomicAdd(&ssum[s5], di);
          unsafeAtomicAdd(&ssum[s6], di);
          unsafeAtomicAdd(&ssum[s7], di);
        }
        f32x2 f0 = __builtin_amdgcn_cvt_pk_f32_fp8((int)v0, false);
        f32x2 f1 = __builtin_amdgcn_cvt_pk_f32_fp8((int)v1, false);
        f32x2 f2 = __builtin_amdgcn_cvt_pk_f32_fp8((int)v2, false);
        f32x2 f3 = __builtin_amdgcn_cvt_pk_f32_fp8((int)v3, false);
        f32x2 f4 = __builtin_amdgcn_cvt_pk_f32_fp8((int)v4, false);
        f32x2 f5 = __builtin_amdgcn_cvt_pk_f32_fp8((int)v5, false);
        f32x2 f6 = __builtin_amdgcn_cvt_pk_f32_fp8((int)v6, false);
        f32x2 f7 = __builtin_amdgcn_cvt_pk_f32_fp8((int)v7, false);
        ax[k] = fmaf(e0, f0.x, ax[k]);
        ay[k] = fmaf(e0, f0.y, ay[k]);
        ax[k] = fmaf(e1, f1.x, ax[k]);
        ay[k] = fmaf(e1, f1.y, ay[k]);
        ax[k] = fmaf(e2, f2.x, ax[k]);
        ay[k] = fmaf(e2, f2.y, ay[k]);
        ax[k] = fmaf(e3, f3.x, ax[k]);
        ay[k] = fmaf(e3, f3.y, ay[k]);
        ax[k] = fmaf(e4, f4.x, ax[k]);
        ay[k] = fmaf(e4, f4.y, ay[k]);
        ax[k] = fmaf(e5, f5.x, ax[k]);
        ay[k] = fmaf(e5, f5.y, ay[k]);
        ax[k] = fmaf(e6, f6.x, ax[k]);
        ay[k] = fmaf(e6, f6.y, ay[k]);
        ax[k] = fmaf(e7, f7.x, ax[k]);
        ay[k] = fmaf(e7, f7.y, ay[k]);
      }
      for (; j < end; ++j) {
        int s = srt[j];
        float e = dinv[s];
        unsigned v = hu8[(size_t)s * 64 + lane];
        if (lane == 0) unsafeAtomicAdd(&ssum[s], di);
        f32x2 f = __builtin_amdgcn_cvt_pk_f32_fp8((int)v, false);
        ax[k] = fmaf(e, f.x, ax[k]);
        ay[k] = fmaf(e, f.y, ay[k]);
      }
    }
    __syncthreads();
  }

  // epilogue: a1 = relu(di*(acc + di*h_self) + b1), packed bf16
  float2 bb = *(const float2*)(b1 + lane * 2);
  #pragma unroll
  for (int k = 0; k < 8; ++k) {
    int rl = wid + k * 4;
    int r = bkt * RPB + rl;
    if (r >= N) continue;
    float di = dinv[r];
    unsigned gr = hu8[(size_t)r * 64 + lane];
    f32x2 fg = __builtin_amdgcn_cvt_pk_f32_fp8((int)gr, false);
    float hx = fmaxf(fmaf(di, fmaf(di, fg.x, ax[k]), bb.x), 0.f);
    float hy = fmaxf(fmaf(di, fmaf(di, fg.y, ay[k]), bb.y), 0.f);
    a1u[(size_t)r * 64 + lane] = pack2(hx, hy);
  }
}

// ---------------- weighted reduce: vpart[blk] = sum_r dinv[r]*(ssum[r]+dinv[r])*a1[r]
__global__ __launch_bounds__(256) void k_vred(const unsigned* __restrict__ a1u,
                                              const float* __restrict__ dinv,
                                              const float* __restrict__ ssum,
                                              float* __restrict__ vpart, int N) {
  int lane = threadIdx.x & 63;
  int wid = threadIdx.x >> 6;
  float vx = 0.f, vy = 0.f;
  for (int r = blockIdx.x * 4 + wid; r < N; r += gridDim.x * 4) {
    float di = dinv[r];
    float w = di * (ssum[r] + di);
    unsigned v = a1u[(size_t)r * 64 + lane];
    vx = fmaf(w, unpk_lo(v), vx);
    vy = fmaf(w, unpk_hi(v), vy);
  }
  __shared__ float2 red[256];
  red[threadIdx.x] = make_float2(vx, vy);
  __syncthreads();
  if (threadIdx.x < 64) {
    float2 a = red[threadIdx.x], b = red[threadIdx.x + 64];
    float2 c = red[threadIdx.x + 128], d = red[threadIdx.x + 192];
    float2 o = make_float2((a.x + b.x) + (c.x + d.x), (a.y + b.y) + (c.y + d.y));
    *(float2*)(vpart + (size_t)blockIdx.x * D + lane * 2) = o;
  }
}

// ---------------- final: v = sum partials; out = (1/N)*v@W2 + b2
__global__ __launch_bounds__(1024) void k_final(const float* __restrict__ vpart,
                                                int npart,
                                                const float* __restrict__ W2,
                                                const float* __restrict__ b2,
                                                float* __restrict__ out, float invN) {
  __shared__ float seg[8][128];
  __shared__ float vs[128];
  int t = threadIdx.x;
  int c = t & 127, sg = t >> 7;
  float s = 0.f;
  for (int b = sg; b < npart; b += 8) s += vpart[(size_t)b * D + c];
  seg[sg][c] = s;
  __syncthreads();
  if (t < 128) {
    float tot = 0.f;
    #pragma unroll
    for (int k = 0; k < 8; ++k) tot += seg[k][c];
    vs[c] = tot;
  }
  __syncthreads();
  if (t < 128) {
    float o = 0.f;
    for (int k = 0; k < 128; ++k) o = fmaf(vs[k], W2[k * D + c], o);
    out[c] = fmaf(o, invN, b2[c]);
  }
}

extern "C" void kernel_launch(void* const* d_in, const int* in_sizes, int n_in,
                              void* d_out, int out_size, void* d_ws, size_t ws_size,
                              hipStream_t stream) {
  const float* x  = (const float*)d_in[0];
  const int*   ei = (const int*)d_in[1];
  const float* W1 = (const float*)d_in[2];
  const float* b1 = (const float*)d_in[3];
  const float* W2 = (const float*)d_in[4];
  const float* b2 = (const float*)d_in[5];
  float* out = (float*)d_out;

  int N = in_sizes[0] / D;
  int E = in_sizes[1] / 2;
  const int* src = ei;
  const int* dst = ei + E;

  const int NBKT = (N + RPB - 1) / RPB;                    // 3125
  const int ECH  = (((E + PB - 1) / PB) + 3) & ~3;         // 6252 (x4 aligned)
  const int T    = NBKT * PB;                              // 800000
  const int NSC  = (T + 4095) / 4096;                      // 196 (<= 256)
  const int NGEMM = (N + 63) / 64;                         // 1563
  const int VRED_BLOCKS = 256;

  char* p = (char*)d_ws;
  float* ssum  = (float*)p;      p += (size_t)N * 4;
  float* dinv  = (float*)p;      p += (size_t)N * 4;
  int*   bsumP = (int*)p;        p += 512 * 4;
  int*   phT   = (int*)p;        p += (size_t)T * 4;
  int*   eb    = (int*)p;        p += (size_t)E * 4;
  p = (char*)(((uintptr_t)p + 255) & ~(uintptr_t)255);
  unsigned short* Wtg = (unsigned short*)p;  p += 128 * 128 * 2;
  p = (char*)(((uintptr_t)p + 255) & ~(uintptr_t)255);
  unsigned short* hu8 = (unsigned short*)p;  p += (size_t)N * 64 * 2;
  p = (char*)(((uintptr_t)p + 255) & ~(uintptr_t)255);
  unsigned* a1u = (unsigned*)p;  p += (size_t)N * 64 * 4;
  float* vpart  = (float*)p;

  k_hist<<<PB + 64, 256, 0, stream>>>(dst, phT, ssum, W1, Wtg, N, E, NBKT, ECH);

  k_mid<<<NSC, 256, 0, stream>>>(phT, bsumP, T);

  k_scanC<<<NSC, 256, 0, stream>>>(phT, bsumP, NSC, T);

  k_scat_gemm<<<PB + NGEMM, 256, 0, stream>>>(src, dst, phT, eb, x, Wtg, hu8,
                                              N, E, NBKT, ECH);

  k_rowdeg<<<NBKT, 256, 0, stream>>>(eb, phT, dinv, N, E, NBKT);

  k_bagg<<<NBKT, 256, 0, stream>>>(hu8, eb, phT, dinv, ssum, b1, a1u, N, E, NBKT);

  k_vred<<<VRED_BLOCKS, 256, 0, stream>>>(a1u, dinv, ssum, vpart, N);

  k_final<<<1, 1024, 0, stream>>>(vpart, VRED_BLOCKS, W2, b2, out, 1.0f / N);
}

// Round 13
// 336.695 us; speedup vs baseline: 1.0003x; 1.0003x over previous
//
#include <hip/hip_runtime.h>

#define D 128
#define RPB 32          // rows per bucket
#define SHIFT 5         // log2(RPB)
#define PB 256          // partition blocks
#define CAP 1536        // max edges per bucket chunk (avg 512)

typedef __attribute__((ext_vector_type(8))) short short8;
typedef __attribute__((ext_vector_type(4))) float f32x4;
typedef __attribute__((ext_vector_type(2))) float f32x2;

// ---- bf16 pack helpers (round-to-nearest-even)
__device__ inline unsigned bfr(float f) {
  unsigned u = __float_as_uint(f);
  return (u + 0x7fffu + ((u >> 16) & 1u)) >> 16;
}
__device__ inline unsigned pack2(float lo, float hi) {
  return bfr(lo) | (bfr(hi) << 16);
}
__device__ inline float unpk_lo(unsigned v) { return __uint_as_float(v << 16); }
__device__ inline float unpk_hi(unsigned v) { return __uint_as_float(v & 0xffff0000u); }

// ---------------- hist: dual LDS histograms (dst buckets + src buckets) in one pass;
// role B (64 blocks): W1 fp32 -> bf16 transposed Wtg
__global__ __launch_bounds__(256) void k_hist(const int* __restrict__ dst,
                                              const int* __restrict__ src,
                                              int* __restrict__ phT,
                                              const float* __restrict__ W,
                                              unsigned short* __restrict__ Wtg,
                                              int E, int NBKT, int ECH, int T) {
  __shared__ int hist[6400];  // 2*NBKT <= 6400
  int b = blockIdx.x, t = threadIdx.x;
  if (b >= PB) {
    int i = (b - PB) * 256 + t;
    if (i < 128 * 128) {
      int k = i >> 7, n = i & 127;
      Wtg[n * 128 + k] = (unsigned short)bfr(W[k * 128 + n]);
    }
    return;
  }
  int* histD = hist;
  int* histS = hist + NBKT;
  for (int k = t; k < 2 * NBKT; k += 256) hist[k] = 0;
  __syncthreads();
  int st = b * ECH, en = min(E, st + ECH);
  for (int i = st + t; i < en; i += 256) {
    atomicAdd(&histD[dst[i] >> SHIFT], 1);
    atomicAdd(&histS[src[i] >> SHIFT], 1);
  }
  __syncthreads();
  for (int k = t; k < NBKT; k += 256) {
    phT[k * PB + b] = histD[k];
    phT[T + k * PB + b] = histS[k];
  }
}

// ---------------- mid: per-8192-chunk sums of phT (covers both tables, 2T entries)
__global__ __launch_bounds__(256) void k_mid(const int* __restrict__ phT,
                                             int* __restrict__ bsumP, int T2) {
  int t = threadIdx.x;
  int base = blockIdx.x * 8192 + t * 32;
  int s = 0;
  #pragma unroll
  for (int j = 0; j < 32; ++j) {
    int idx = base + j;
    if (idx < T2) s += phT[idx];
  }
  __shared__ int red[256];
  red[t] = s;
  __syncthreads();
  for (int off = 128; off > 0; off >>= 1) {
    if (t < off) red[t] += red[t + off];
    __syncthreads();
  }
  if (t == 0) bsumP[blockIdx.x] = red[0];
}

// ---------------- scanC: in-place exclusive scan of phT (2T entries)
__global__ __launch_bounds__(256) void k_scanC(int* __restrict__ phT,
                                               const int* __restrict__ bsumP,
                                               int nsc, int T2) {
  int t = threadIdx.x;
  __shared__ int sc2[256];
  sc2[t] = (t < nsc) ? bsumP[t] : 0;
  __syncthreads();
  #pragma unroll
  for (int off = 1; off < 256; off <<= 1) {
    int x = (t >= off) ? sc2[t - off] : 0;
    __syncthreads();
    sc2[t] += x;
    __syncthreads();
  }
  int bbase = (blockIdx.x == 0) ? 0 : sc2[blockIdx.x - 1];

  int base = blockIdx.x * 8192 + t * 32;
  int v[32];
  int s = 0;
  #pragma unroll
  for (int j = 0; j < 32; ++j) {
    int idx = base + j;
    v[j] = (idx < T2) ? phT[idx] : 0;
    s += v[j];
  }
  __shared__ int sc[256];
  sc[t] = s;
  __syncthreads();
  for (int off = 1; off < 256; off <<= 1) {
    int x = (t >= off) ? sc[t - off] : 0;
    __syncthreads();
    sc[t] += x;
    __syncthreads();
  }
  int p = bbase + sc[t] - s;
  #pragma unroll
  for (int j = 0; j < 32; ++j) {
    int idx = base + j;
    if (idx < T2) {
      phT[idx] = p;
      p += v[j];
    }
  }
}

// ---------------- FUSED: dual pscat (role A, PB blocks) || MFMA gemm (role B)
// dst-partition: eb[0..E) = src|(dstloc<<26); src-partition: eb[E..2E) = dst|(srcloc<<26)
__global__ __launch_bounds__(256) void k_scat_gemm(
    const int* __restrict__ src, const int* __restrict__ dst,
    const int* __restrict__ phT, int* __restrict__ eb,
    const float* __restrict__ x, const unsigned short* __restrict__ Wtg,
    unsigned short* __restrict__ hu8, int M, int E, int NBKT, int ECH, int T) {
  __shared__ int shm[6400];  // 25.6 KB: 2*NBKT cursors or gemm x-tile
  int b = blockIdx.x, t = threadIdx.x;

  if (b < PB) {
    int* curD = shm;
    int* curS = shm + NBKT;
    for (int k = t; k < NBKT; k += 256) {
      curD[k] = phT[k * PB + b];
      curS[k] = phT[T + k * PB + b];
    }
    __syncthreads();
    int st = b * ECH, en = min(E, st + ECH);
    for (int i = st + t * 4; i < en; i += 1024) {
      if (i + 3 < en) {
        int4 s4 = *(const int4*)(src + i);
        int4 d4 = *(const int4*)(dst + i);
        int p0 = atomicAdd(&curD[d4.x >> SHIFT], 1);
        int p1 = atomicAdd(&curD[d4.y >> SHIFT], 1);
        int p2 = atomicAdd(&curD[d4.z >> SHIFT], 1);
        int p3 = atomicAdd(&curD[d4.w >> SHIFT], 1);
        eb[p0] = s4.x | ((d4.x & (RPB - 1)) << 26);
        eb[p1] = s4.y | ((d4.y & (RPB - 1)) << 26);
        eb[p2] = s4.z | ((d4.z & (RPB - 1)) << 26);
        eb[p3] = s4.w | ((d4.w & (RPB - 1)) << 26);
        int q0 = atomicAdd(&curS[s4.x >> SHIFT], 1);
        int q1 = atomicAdd(&curS[s4.y >> SHIFT], 1);
        int q2 = atomicAdd(&curS[s4.z >> SHIFT], 1);
        int q3 = atomicAdd(&curS[s4.w >> SHIFT], 1);
        eb[q0] = d4.x | ((s4.x & (RPB - 1)) << 26);
        eb[q1] = d4.y | ((s4.y & (RPB - 1)) << 26);
        eb[q2] = d4.z | ((s4.z & (RPB - 1)) << 26);
        eb[q3] = d4.w | ((s4.w & (RPB - 1)) << 26);
      } else {
        for (int j = i; j < en; ++j) {
          int d = dst[j], s = src[j];
          int pos = atomicAdd(&curD[d >> SHIFT], 1);
          eb[pos] = s | ((d & (RPB - 1)) << 26);
          int qos = atomicAdd(&curS[s >> SHIFT], 1);
          eb[qos] = d | ((s & (RPB - 1)) << 26);
        }
      }
    }
    return;
  }

  // ---- MFMA gemm role: h = x@W1 (unscaled), fp8 e4m3 packed
  int row0 = (b - PB) * 64;
  if (row0 >= M) return;
  unsigned short* xs = (unsigned short*)shm;  // [64][136]

  for (int i = t; i < 2048; i += 256) {
    int r = i >> 5;
    int rg = row0 + r;
    int rc = rg < M ? rg : M - 1;
    float4 v = ((const float4*)x)[(size_t)rc * 32 + (i & 31)];
    *(uint2*)&xs[r * 136 + (i & 31) * 4] = make_uint2(pack2(v.x, v.y), pack2(v.z, v.w));
  }
  __syncthreads();

  int lane = t & 63;
  int wid = t >> 6;
  int l15 = lane & 15;
  int quad = lane >> 4;
  int mloc = wid * 16 + l15;

  f32x4 acc[8];
  #pragma unroll
  for (int ct = 0; ct < 8; ++ct) acc[ct] = (f32x4){0.f, 0.f, 0.f, 0.f};

  #pragma unroll
  for (int k0 = 0; k0 < 128; k0 += 32) {
    short8 af = *(const short8*)&xs[mloc * 136 + k0 + quad * 8];
    #pragma unroll
    for (int ct = 0; ct < 8; ++ct) {
      short8 bf = *(const short8*)(Wtg + (ct * 16 + l15) * 128 + k0 + quad * 8);
      acc[ct] = __builtin_amdgcn_mfma_f32_16x16x32_bf16(af, bf, acc[ct], 0, 0, 0);
    }
  }

  int rowbase = row0 + wid * 16 + quad * 4;
  #pragma unroll
  for (int ct = 0; ct < 8; ++ct) {
    #pragma unroll
    for (int r = 0; r < 4; ++r) {
      float v = acc[ct][r];
      float vp = __shfl_xor(v, 1, 64);
      int row = rowbase + r;
      if (!(lane & 1) && row < M) {
        int pk = __builtin_amdgcn_cvt_pk_fp8_f32(v, vp, 0, false);
        hu8[(size_t)row * 64 + ct * 8 + (l15 >> 1)] = (unsigned short)(pk & 0xffff);
      }
    }
  }
}

// ---------------- rowdeg: per-dst-bucket LDS count of local rows -> dinv
__global__ __launch_bounds__(256) void k_rowdeg(const int* __restrict__ eb,
                                                const int* __restrict__ phT,
                                                float* __restrict__ dinv,
                                                int N, int E, int NBKT) {
  __shared__ int cnt[RPB];
  int bkt = blockIdx.x, t = threadIdx.x;
  if (t < RPB) cnt[t] = 0;
  __syncthreads();
  int lo = phT[bkt * PB];
  int hi = (bkt + 1 < NBKT) ? phT[(bkt + 1) * PB] : E;
  for (int i = lo + t; i < hi; i += 256)
    atomicAdd(&cnt[(unsigned)eb[i] >> 26], 1);
  __syncthreads();
  if (t < RPB) {
    int r = bkt * RPB + t;
    if (r < N) dinv[r] = rsqrtf((float)cnt[t] + 1.0f);
  }
}

// ---------------- bucketed aggregate (blocks < NBKT) + ssum accumulation (blocks >= NBKT)
__global__ __launch_bounds__(256) void k_bagg(
    const unsigned short* __restrict__ hu8, const int* __restrict__ eb,
    const int* __restrict__ phT, const float* __restrict__ dinv,
    float* __restrict__ ssum, const float* __restrict__ b1,
    unsigned* __restrict__ a1u, int N, int E, int NBKT, int T) {
  __shared__ int raw[CAP];
  __shared__ int srt[CAP];
  __shared__ int rh[RPB + 1];
  __shared__ int rcur[RPB];
  int bkt = blockIdx.x, t = threadIdx.x;

  if (bkt >= NBKT) {
    // ---- ssum role (src partition): ssum[r] = sum dinv[dst] over out-edges of r
    int sb = bkt - NBKT;
    float* sums = (float*)rcur;
    if (t < RPB) sums[t] = 0.f;
    __syncthreads();
    int lo = phT[T + sb * PB];
    int hi = (sb + 1 < NBKT) ? phT[T + (sb + 1) * PB] : 2 * E;
    for (int i = lo + t; i < hi; i += 256) {
      int v = eb[i];
      atomicAdd(&sums[(unsigned)v >> 26], dinv[v & 0x3FFFFFF]);
    }
    __syncthreads();
    if (t < RPB) {
      int r = sb * RPB + t;
      if (r < N) ssum[r] = sums[t];
    }
    return;
  }

  int lane = t & 63, wid = t >> 6;
  int lo = phT[bkt * PB];
  int hi = (bkt + 1 < NBKT) ? phT[(bkt + 1) * PB] : E;

  float ax[8], ay[8];
  #pragma unroll
  for (int k = 0; k < 8; ++k) { ax[k] = 0.f; ay[k] = 0.f; }

  for (int clo = lo; clo < hi; clo += CAP) {
    int cnt = min(CAP, hi - clo);
    if (t <= RPB) rh[t] = 0;
    __syncthreads();
    for (int i = t; i < cnt; i += 256) {
      int v = eb[clo + i];
      raw[i] = v;
      atomicAdd(&rh[((unsigned)v >> 26) + 1], 1);
    }
    __syncthreads();
    if (t < 32) {
      int x = rh[t + 1];
      #pragma unroll
      for (int o = 1; o < 32; o <<= 1) {
        int y = __shfl_up(x, o, 64);
        if (t >= o) x += y;
      }
      rh[t + 1] = x;
    }
    __syncthreads();
    if (t < RPB) rcur[t] = rh[t];
    __syncthreads();
    for (int i = t; i < cnt; i += 256) {
      int v = raw[i];
      int r = (unsigned)v >> 26;
      int pos = atomicAdd(&rcur[r], 1);
      srt[pos] = v & 0x3FFFFFF;
    }
    __syncthreads();

    #pragma unroll
    for (int k = 0; k < 8; ++k) {
      int rl = wid + k * 4;
      int beg = rh[rl], end = rh[rl + 1];
      int j = beg;
      for (; j + 8 <= end; j += 8) {
        int s0 = srt[j], s1 = srt[j + 1], s2 = srt[j + 2], s3 = srt[j + 3];
        int s4 = srt[j + 4], s5 = srt[j + 5], s6 = srt[j + 6], s7 = srt[j + 7];
        float e0 = dinv[s0], e1 = dinv[s1], e2 = dinv[s2], e3 = dinv[s3];
        float e4 = dinv[s4], e5 = dinv[s5], e6 = dinv[s6], e7 = dinv[s7];
        unsigned v0 = hu8[(size_t)s0 * 64 + lane];
        unsigned v1 = hu8[(size_t)s1 * 64 + lane];
        unsigned v2 = hu8[(size_t)s2 * 64 + lane];
        unsigned v3 = hu8[(size_t)s3 * 64 + lane];
        unsigned v4 = hu8[(size_t)s4 * 64 + lane];
        unsigned v5 = hu8[(size_t)s5 * 64 + lane];
        unsigned v6 = hu8[(size_t)s6 * 64 + lane];
        unsigned v7 = hu8[(size_t)s7 * 64 + lane];
        f32x2 f0 = __builtin_amdgcn_cvt_pk_f32_fp8((int)v0, false);
        f32x2 f1 = __builtin_amdgcn_cvt_pk_f32_fp8((int)v1, false);
        f32x2 f2 = __builtin_amdgcn_cvt_pk_f32_fp8((int)v2, false);
        f32x2 f3 = __builtin_amdgcn_cvt_pk_f32_fp8((int)v3, false);
        f32x2 f4 = __builtin_amdgcn_cvt_pk_f32_fp8((int)v4, false);
        f32x2 f5 = __builtin_amdgcn_cvt_pk_f32_fp8((int)v5, false);
        f32x2 f6 = __builtin_amdgcn_cvt_pk_f32_fp8((int)v6, false);
        f32x2 f7 = __builtin_amdgcn_cvt_pk_f32_fp8((int)v7, false);
        ax[k] = fmaf(e0, f0.x, ax[k]);
        ay[k] = fmaf(e0, f0.y, ay[k]);
        ax[k] = fmaf(e1, f1.x, ax[k]);
        ay[k] = fmaf(e1, f1.y, ay[k]);
        ax[k] = fmaf(e2, f2.x, ax[k]);
        ay[k] = fmaf(e2, f2.y, ay[k]);
        ax[k] = fmaf(e3, f3.x, ax[k]);
        ay[k] = fmaf(e3, f3.y, ay[k]);
        ax[k] = fmaf(e4, f4.x, ax[k]);
        ay[k] = fmaf(e4, f4.y, ay[k]);
        ax[k] = fmaf(e5, f5.x, ax[k]);
        ay[k] = fmaf(e5, f5.y, ay[k]);
        ax[k] = fmaf(e6, f6.x, ax[k]);
        ay[k] = fmaf(e6, f6.y, ay[k]);
        ax[k] = fmaf(e7, f7.x, ax[k]);
        ay[k] = fmaf(e7, f7.y, ay[k]);
      }
      for (; j < end; ++j) {
        int s = srt[j];
        float e = dinv[s];
        unsigned v = hu8[(size_t)s * 64 + lane];
        f32x2 f = __builtin_amdgcn_cvt_pk_f32_fp8((int)v, false);
        ax[k] = fmaf(e, f.x, ax[k]);
        ay[k] = fmaf(e, f.y, ay[k]);
      }
    }
    __syncthreads();
  }

  // epilogue: a1 = relu(di*(acc + di*h_self) + b1), packed bf16
  float2 bb = *(const float2*)(b1 + lane * 2);
  #pragma unroll
  for (int k = 0; k < 8; ++k) {
    int rl = wid + k * 4;
    int r = bkt * RPB + rl;
    if (r >= N) continue;
    float di = dinv[r];
    unsigned gr = hu8[(size_t)r * 64 + lane];
    f32x2 fg = __builtin_amdgcn_cvt_pk_f32_fp8((int)gr, false);
    float hx = fmaxf(fmaf(di, fmaf(di, fg.x, ax[k]), bb.x), 0.f);
    float hy = fmaxf(fmaf(di, fmaf(di, fg.y, ay[k]), bb.y), 0.f);
    a1u[(size_t)r * 64 + lane] = pack2(hx, hy);
  }
}

// ---------------- weighted reduce: vpart[blk] = sum_r dinv[r]*(ssum[r]+dinv[r])*a1[r]
__global__ __launch_bounds__(256) void k_vred(const unsigned* __restrict__ a1u,
                                              const float* __restrict__ dinv,
                                              const float* __restrict__ ssum,
                                              float* __restrict__ vpart, int N) {
  int lane = threadIdx.x & 63;
  int wid = threadIdx.x >> 6;
  float vx = 0.f, vy = 0.f;
  for (int r = blockIdx.x * 4 + wid; r < N; r += gridDim.x * 4) {
    float di = dinv[r];
    float w = di * (ssum[r] + di);
    unsigned v = a1u[(size_t)r * 64 + lane];
    vx = fmaf(w, unpk_lo(v), vx);
    vy = fmaf(w, unpk_hi(v), vy);
  }
  __shared__ float2 red[256];
  red[threadIdx.x] = make_float2(vx, vy);
  __syncthreads();
  if (threadIdx.x < 64) {
    float2 a = red[threadIdx.x], b = red[threadIdx.x + 64];
    float2 c = red[threadIdx.x + 128], d = red[threadIdx.x + 192];
    float2 o = make_float2((a.x + b.x) + (c.x + d.x), (a.y + b.y) + (c.y + d.y));
    *(float2*)(vpart + (size_t)blockIdx.x * D + lane * 2) = o;
  }
}

// ---------------- final: v = sum partials; out = (1/N)*v@W2 + b2
__global__ __launch_bounds__(1024) void k_final(const float* __restrict__ vpart,
                                                int npart,
                                                const float* __restrict__ W2,
                                                const float* __restrict__ b2,
                                                float* __restrict__ out, float invN) {
  __shared__ float seg[8][128];
  __shared__ float vs[128];
  int t = threadIdx.x;
  int c = t & 127, sg = t >> 7;
  float s = 0.f;
  for (int b = sg; b < npart; b += 8) s += vpart[(size_t)b * D + c];
  seg[sg][c] = s;
  __syncthreads();
  if (t < 128) {
    float tot = 0.f;
    #pragma unroll
    for (int k = 0; k < 8; ++k) tot += seg[k][c];
    vs[c] = tot;
  }
  __syncthreads();
  if (t < 128) {
    float o = 0.f;
    for (int k = 0; k < 128; ++k) o = fmaf(vs[k], W2[k * D + c], o);
    out[c] = fmaf(o, invN, b2[c]);
  }
}

extern "C" void kernel_launch(void* const* d_in, const int* in_sizes, int n_in,
                              void* d_out, int out_size, void* d_ws, size_t ws_size,
                              hipStream_t stream) {
  const float* x  = (const float*)d_in[0];
  const int*   ei = (const int*)d_in[1];
  const float* W1 = (const float*)d_in[2];
  const float* b1 = (const float*)d_in[3];
  const float* W2 = (const float*)d_in[4];
  const float* b2 = (const float*)d_in[5];
  float* out = (float*)d_out;

  int N = in_sizes[0] / D;
  int E = in_sizes[1] / 2;
  const int* src = ei;
  const int* dst = ei + E;

  const int NBKT = (N + RPB - 1) / RPB;                    // 3125
  const int ECH  = (((E + PB - 1) / PB) + 3) & ~3;         // 6252 (x4 aligned)
  const int T    = NBKT * PB;                              // 800000 (one table)
  const int T2   = 2 * T;                                  // both tables
  const int NSC  = (T2 + 8191) / 8192;                     // 196 (<= 256)
  const int NGEMM = (N + 63) / 64;                         // 1563
  const int VRED_BLOCKS = 256;

  char* p = (char*)d_ws;
  float* ssum  = (float*)p;      p += (size_t)N * 4;
  float* dinv  = (float*)p;      p += (size_t)N * 4;
  int*   bsumP = (int*)p;        p += 512 * 4;
  int*   phT   = (int*)p;        p += (size_t)T2 * 4;
  int*   eb    = (int*)p;        p += (size_t)(2 * E) * 4;
  p = (char*)(((uintptr_t)p + 255) & ~(uintptr_t)255);
  unsigned short* Wtg = (unsigned short*)p;  p += 128 * 128 * 2;
  p = (char*)(((uintptr_t)p + 255) & ~(uintptr_t)255);
  unsigned short* hu8 = (unsigned short*)p;  p += (size_t)N * 64 * 2;
  p = (char*)(((uintptr_t)p + 255) & ~(uintptr_t)255);
  unsigned* a1u = (unsigned*)p;  p += (size_t)N * 64 * 4;
  float* vpart  = (float*)p;

  k_hist<<<PB + 64, 256, 0, stream>>>(dst, src, phT, W1, Wtg, E, NBKT, ECH, T);

  k_mid<<<NSC, 256, 0, stream>>>(phT, bsumP, T2);

  k_scanC<<<NSC, 256, 0, stream>>>(phT, bsumP, NSC, T2);

  k_scat_gemm<<<PB + NGEMM, 256, 0, stream>>>(src, dst, phT, eb, x, Wtg, hu8,
                                              N, E, NBKT, ECH, T);

  k_rowdeg<<<NBKT, 256, 0, stream>>>(eb, phT, dinv, N, E, NBKT);

  k_bagg<<<2 * NBKT, 256, 0, stream>>>(hu8, eb, phT, dinv, ssum, b1, a1u,
                                       N, E, NBKT, T);

  k_vred<<<VRED_BLOCKS, 256, 0, stream>>>(a1u, dinv, ssum, vpart, N);

  k_final<<<1, 1024, 0, stream>>>(vpart, VRED_BLOCKS, W2, b2, out, 1.0f / N);
}

// Round 14
// 313.310 us; speedup vs baseline: 1.0750x; 1.0746x over previous
//
#include <hip/hip_runtime.h>

#define D 128
#define RPB 32          // rows per bucket
#define SHIFT 5         // log2(RPB)
#define PB 256          // partition blocks
#define CAP 1536        // max edges per bucket chunk (avg 512)

typedef __attribute__((ext_vector_type(8))) short short8;
typedef __attribute__((ext_vector_type(4))) float f32x4;
typedef __attribute__((ext_vector_type(2))) float f32x2;

// ---- bf16 pack helpers (round-to-nearest-even)
__device__ inline unsigned bfr(float f) {
  unsigned u = __float_as_uint(f);
  return (u + 0x7fffu + ((u >> 16) & 1u)) >> 16;
}
__device__ inline unsigned pack2(float lo, float hi) {
  return bfr(lo) | (bfr(hi) << 16);
}
__device__ inline float unpk_lo(unsigned v) { return __uint_as_float(v << 16); }
__device__ inline float unpk_hi(unsigned v) { return __uint_as_float(v & 0xffff0000u); }

// ---------------- hist: dual LDS histograms; phT layout [block][bucket] (coalesced rows)
// role B (64 blocks): W1 fp32 -> bf16 transposed Wtg
__global__ __launch_bounds__(256) void k_hist(const int* __restrict__ dst,
                                              const int* __restrict__ src,
                                              int* __restrict__ phT,
                                              const float* __restrict__ W,
                                              unsigned short* __restrict__ Wtg,
                                              int E, int NBKT, int ECH, int K2) {
  __shared__ int hist[6400];
  int b = blockIdx.x, t = threadIdx.x;
  if (b >= PB) {
    int i = (b - PB) * 256 + t;
    if (i < 128 * 128) {
      int k = i >> 7, n = i & 127;
      Wtg[n * 128 + k] = (unsigned short)bfr(W[k * 128 + n]);
    }
    return;
  }
  int* histD = hist;
  int* histS = hist + NBKT;
  for (int k = t; k < K2; k += 256) hist[k] = 0;
  __syncthreads();
  int st = b * ECH, en = min(E, st + ECH);
  for (int i = st + t; i < en; i += 256) {
    atomicAdd(&histD[dst[i] >> SHIFT], 1);
    atomicAdd(&histS[src[i] >> SHIFT], 1);
  }
  __syncthreads();
  for (int k = t; k < K2; k += 256) phT[(size_t)b * K2 + k] = hist[k];
}

// ---------------- tots: per-bucket totals over blocks (coalesced column sums)
__global__ __launch_bounds__(256) void k_tots(const int* __restrict__ phT,
                                              int* __restrict__ tot, int K2) {
  int k = blockIdx.x * 256 + threadIdx.x;
  if (k < K2) {
    int s = 0;
    for (int b = 0; b < PB; ++b) s += phT[(size_t)b * K2 + k];
    tot[k] = s;
  }
}

// ---------------- scan3: redundant in-LDS exclusive scan of tot (K2 entries),
// then per-bucket column rewrite of phT to running prefixes
__global__ __launch_bounds__(256) void k_scan3(int* __restrict__ phT,
                                               const int* __restrict__ tot, int K2) {
  __shared__ int ltot[6400];
  __shared__ int sc[256];
  int t = threadIdx.x;
  for (int i = t; i < K2; i += 256) ltot[i] = tot[i];
  __syncthreads();
  int C = (K2 + 255) / 256;
  int c0 = t * C;
  int s = 0;
  for (int j = 0; j < C; ++j) {
    int idx = c0 + j;
    if (idx < K2) s += ltot[idx];
  }
  sc[t] = s;
  __syncthreads();
  for (int off = 1; off < 256; off <<= 1) {
    int x = (t >= off) ? sc[t - off] : 0;
    __syncthreads();
    sc[t] += x;
    __syncthreads();
  }
  int run = sc[t] - s;  // exclusive base for this thread's chunk
  for (int j = 0; j < C; ++j) {
    int idx = c0 + j;
    if (idx < K2) {
      int v = ltot[idx];
      ltot[idx] = run;
      run += v;
    }
  }
  __syncthreads();

  int k = blockIdx.x * 256 + t;
  if (k < K2) {
    int r = ltot[k];
    for (int b = 0; b < PB; ++b) {
      size_t idx = (size_t)b * K2 + k;
      int v = phT[idx];
      phT[idx] = r;
      r += v;
    }
  }
}

// ---------------- FUSED: dual pscat (role A, PB blocks, XCD-remapped) || MFMA gemm
__global__ __launch_bounds__(256) void k_scat_gemm(
    const int* __restrict__ src, const int* __restrict__ dst,
    const int* __restrict__ phT, int* __restrict__ eb,
    const float* __restrict__ x, const unsigned short* __restrict__ Wtg,
    unsigned short* __restrict__ hu8, int M, int E, int NBKT, int ECH, int K2) {
  __shared__ int shm[6400];  // 25.6 KB: cursors or gemm x-tile
  int p = blockIdx.x, t = threadIdx.x;

  if (p < PB) {
    // XCD-aware remap: consecutive logical chunks (which share eb cachelines)
    // land on the same XCD (blockIdx % 8 == XCD, round-robin dispatch).
    int b = ((p & 7) << 5) | (p >> 3);
    int* curD = shm;
    int* curS = shm + NBKT;
    for (int k = t; k < K2; k += 256) shm[k] = phT[(size_t)b * K2 + k];
    __syncthreads();
    int st = b * ECH, en = min(E, st + ECH);
    for (int i = st + t * 4; i < en; i += 1024) {
      if (i + 3 < en) {
        int4 s4 = *(const int4*)(src + i);
        int4 d4 = *(const int4*)(dst + i);
        int p0 = atomicAdd(&curD[d4.x >> SHIFT], 1);
        int p1 = atomicAdd(&curD[d4.y >> SHIFT], 1);
        int p2 = atomicAdd(&curD[d4.z >> SHIFT], 1);
        int p3 = atomicAdd(&curD[d4.w >> SHIFT], 1);
        eb[p0] = s4.x | ((d4.x & (RPB - 1)) << 26);
        eb[p1] = s4.y | ((d4.y & (RPB - 1)) << 26);
        eb[p2] = s4.z | ((d4.z & (RPB - 1)) << 26);
        eb[p3] = s4.w | ((d4.w & (RPB - 1)) << 26);
        int q0 = atomicAdd(&curS[s4.x >> SHIFT], 1);
        int q1 = atomicAdd(&curS[s4.y >> SHIFT], 1);
        int q2 = atomicAdd(&curS[s4.z >> SHIFT], 1);
        int q3 = atomicAdd(&curS[s4.w >> SHIFT], 1);
        eb[q0] = d4.x | ((s4.x & (RPB - 1)) << 26);
        eb[q1] = d4.y | ((s4.y & (RPB - 1)) << 26);
        eb[q2] = d4.z | ((s4.z & (RPB - 1)) << 26);
        eb[q3] = d4.w | ((s4.w & (RPB - 1)) << 26);
      } else {
        for (int j = i; j < en; ++j) {
          int d = dst[j], s = src[j];
          int pos = atomicAdd(&curD[d >> SHIFT], 1);
          eb[pos] = s | ((d & (RPB - 1)) << 26);
          int qos = atomicAdd(&curS[s >> SHIFT], 1);
          eb[qos] = d | ((s & (RPB - 1)) << 26);
        }
      }
    }
    return;
  }

  // ---- MFMA gemm role: h = x@W1 (unscaled), fp8 e4m3 packed
  int row0 = (p - PB) * 64;
  if (row0 >= M) return;
  unsigned short* xs = (unsigned short*)shm;  // [64][136]

  for (int i = t; i < 2048; i += 256) {
    int r = i >> 5;
    int rg = row0 + r;
    int rc = rg < M ? rg : M - 1;
    float4 v = ((const float4*)x)[(size_t)rc * 32 + (i & 31)];
    *(uint2*)&xs[r * 136 + (i & 31) * 4] = make_uint2(pack2(v.x, v.y), pack2(v.z, v.w));
  }
  __syncthreads();

  int lane = t & 63;
  int wid = t >> 6;
  int l15 = lane & 15;
  int quad = lane >> 4;
  int mloc = wid * 16 + l15;

  f32x4 acc[8];
  #pragma unroll
  for (int ct = 0; ct < 8; ++ct) acc[ct] = (f32x4){0.f, 0.f, 0.f, 0.f};

  #pragma unroll
  for (int k0 = 0; k0 < 128; k0 += 32) {
    short8 af = *(const short8*)&xs[mloc * 136 + k0 + quad * 8];
    #pragma unroll
    for (int ct = 0; ct < 8; ++ct) {
      short8 bf = *(const short8*)(Wtg + (ct * 16 + l15) * 128 + k0 + quad * 8);
      acc[ct] = __builtin_amdgcn_mfma_f32_16x16x32_bf16(af, bf, acc[ct], 0, 0, 0);
    }
  }

  int rowbase = row0 + wid * 16 + quad * 4;
  #pragma unroll
  for (int ct = 0; ct < 8; ++ct) {
    #pragma unroll
    for (int r = 0; r < 4; ++r) {
      float v = acc[ct][r];
      float vp = __shfl_xor(v, 1, 64);
      int row = rowbase + r;
      if (!(lane & 1) && row < M) {
        int pk = __builtin_amdgcn_cvt_pk_fp8_f32(v, vp, 0, false);
        hu8[(size_t)row * 64 + ct * 8 + (l15 >> 1)] = (unsigned short)(pk & 0xffff);
      }
    }
  }
}

// ---------------- rowdeg: per-dst-bucket LDS count of local rows -> dinv
__global__ __launch_bounds__(256) void k_rowdeg(const int* __restrict__ eb,
                                                const int* __restrict__ phT,
                                                float* __restrict__ dinv,
                                                int N, int NBKT) {
  __shared__ int cnt[RPB];
  int bkt = blockIdx.x, t = threadIdx.x;
  if (t < RPB) cnt[t] = 0;
  __syncthreads();
  int lo = phT[bkt];
  int hi = phT[bkt + 1];  // phT[NBKT] == E (start of src table)
  for (int i = lo + t; i < hi; i += 256)
    atomicAdd(&cnt[(unsigned)eb[i] >> 26], 1);
  __syncthreads();
  if (t < RPB) {
    int r = bkt * RPB + t;
    if (r < N) dinv[r] = rsqrtf((float)cnt[t] + 1.0f);
  }
}

// ---------------- bucketed aggregate (blocks < NBKT) + ssum accumulation (blocks >= NBKT)
__global__ __launch_bounds__(256) void k_bagg(
    const unsigned short* __restrict__ hu8, const int* __restrict__ eb,
    const int* __restrict__ phT, const float* __restrict__ dinv,
    float* __restrict__ ssum, const float* __restrict__ b1,
    unsigned* __restrict__ a1u, int N, int E, int NBKT, int K2) {
  __shared__ int raw[CAP];
  __shared__ int srt[CAP];
  __shared__ int rh[RPB + 1];
  __shared__ int rcur[RPB];
  int bkt = blockIdx.x, t = threadIdx.x;

  if (bkt >= NBKT) {
    // ---- ssum role (src partition): ssum[r] = sum dinv[dst] over out-edges of r
    int sb = bkt - NBKT;
    float* sums = (float*)rcur;
    if (t < RPB) sums[t] = 0.f;
    __syncthreads();
    int lo = phT[NBKT + sb];
    int hi = (NBKT + sb + 1 < K2) ? phT[NBKT + sb + 1] : 2 * E;
    for (int i = lo + t; i < hi; i += 256) {
      int v = eb[i];
      atomicAdd(&sums[(unsigned)v >> 26], dinv[v & 0x3FFFFFF]);
    }
    __syncthreads();
    if (t < RPB) {
      int r = sb * RPB + t;
      if (r < N) ssum[r] = sums[t];
    }
    return;
  }

  int lane = t & 63, wid = t >> 6;
  int lo = phT[bkt];
  int hi = phT[bkt + 1];

  float ax[8], ay[8];
  #pragma unroll
  for (int k = 0; k < 8; ++k) { ax[k] = 0.f; ay[k] = 0.f; }

  for (int clo = lo; clo < hi; clo += CAP) {
    int cnt = min(CAP, hi - clo);
    if (t <= RPB) rh[t] = 0;
    __syncthreads();
    for (int i = t; i < cnt; i += 256) {
      int v = eb[clo + i];
      raw[i] = v;
      atomicAdd(&rh[((unsigned)v >> 26) + 1], 1);
    }
    __syncthreads();
    if (t < 32) {
      int x = rh[t + 1];
      #pragma unroll
      for (int o = 1; o < 32; o <<= 1) {
        int y = __shfl_up(x, o, 64);
        if (t >= o) x += y;
      }
      rh[t + 1] = x;
    }
    __syncthreads();
    if (t < RPB) rcur[t] = rh[t];
    __syncthreads();
    for (int i = t; i < cnt; i += 256) {
      int v = raw[i];
      int r = (unsigned)v >> 26;
      int pos = atomicAdd(&rcur[r], 1);
      srt[pos] = v & 0x3FFFFFF;
    }
    __syncthreads();

    #pragma unroll
    for (int k = 0; k < 8; ++k) {
      int rl = wid + k * 4;
      int beg = rh[rl], end = rh[rl + 1];
      int j = beg;
      for (; j + 8 <= end; j += 8) {
        int s0 = srt[j], s1 = srt[j + 1], s2 = srt[j + 2], s3 = srt[j + 3];
        int s4 = srt[j + 4], s5 = srt[j + 5], s6 = srt[j + 6], s7 = srt[j + 7];
        float e0 = dinv[s0], e1 = dinv[s1], e2 = dinv[s2], e3 = dinv[s3];
        float e4 = dinv[s4], e5 = dinv[s5], e6 = dinv[s6], e7 = dinv[s7];
        unsigned v0 = hu8[(size_t)s0 * 64 + lane];
        unsigned v1 = hu8[(size_t)s1 * 64 + lane];
        unsigned v2 = hu8[(size_t)s2 * 64 + lane];
        unsigned v3 = hu8[(size_t)s3 * 64 + lane];
        unsigned v4 = hu8[(size_t)s4 * 64 + lane];
        unsigned v5 = hu8[(size_t)s5 * 64 + lane];
        unsigned v6 = hu8[(size_t)s6 * 64 + lane];
        unsigned v7 = hu8[(size_t)s7 * 64 + lane];
        f32x2 f0 = __builtin_amdgcn_cvt_pk_f32_fp8((int)v0, false);
        f32x2 f1 = __builtin_amdgcn_cvt_pk_f32_fp8((int)v1, false);
        f32x2 f2 = __builtin_amdgcn_cvt_pk_f32_fp8((int)v2, false);
        f32x2 f3 = __builtin_amdgcn_cvt_pk_f32_fp8((int)v3, false);
        f32x2 f4 = __builtin_amdgcn_cvt_pk_f32_fp8((int)v4, false);
        f32x2 f5 = __builtin_amdgcn_cvt_pk_f32_fp8((int)v5, false);
        f32x2 f6 = __builtin_amdgcn_cvt_pk_f32_fp8((int)v6, false);
        f32x2 f7 = __builtin_amdgcn_cvt_pk_f32_fp8((int)v7, false);
        ax[k] = fmaf(e0, f0.x, ax[k]);
        ay[k] = fmaf(e0, f0.y, ay[k]);
        ax[k] = fmaf(e1, f1.x, ax[k]);
        ay[k] = fmaf(e1, f1.y, ay[k]);
        ax[k] = fmaf(e2, f2.x, ax[k]);
        ay[k] = fmaf(e2, f2.y, ay[k]);
        ax[k] = fmaf(e3, f3.x, ax[k]);
        ay[k] = fmaf(e3, f3.y, ay[k]);
        ax[k] = fmaf(e4, f4.x, ax[k]);
        ay[k] = fmaf(e4, f4.y, ay[k]);
        ax[k] = fmaf(e5, f5.x, ax[k]);
        ay[k] = fmaf(e5, f5.y, ay[k]);
        ax[k] = fmaf(e6, f6.x, ax[k]);
        ay[k] = fmaf(e6, f6.y, ay[k]);
        ax[k] = fmaf(e7, f7.x, ax[k]);
        ay[k] = fmaf(e7, f7.y, ay[k]);
      }
      for (; j < end; ++j) {
        int s = srt[j];
        float e = dinv[s];
        unsigned v = hu8[(size_t)s * 64 + lane];
        f32x2 f = __builtin_amdgcn_cvt_pk_f32_fp8((int)v, false);
        ax[k] = fmaf(e, f.x, ax[k]);
        ay[k] = fmaf(e, f.y, ay[k]);
      }
    }
    __syncthreads();
  }

  // epilogue: a1 = relu(di*(acc + di*h_self) + b1), packed bf16
  float2 bb = *(const float2*)(b1 + lane * 2);
  #pragma unroll
  for (int k = 0; k < 8; ++k) {
    int rl = wid + k * 4;
    int r = bkt * RPB + rl;
    if (r >= N) continue;
    float di = dinv[r];
    unsigned gr = hu8[(size_t)r * 64 + lane];
    f32x2 fg = __builtin_amdgcn_cvt_pk_f32_fp8((int)gr, false);
    float hx = fmaxf(fmaf(di, fmaf(di, fg.x, ax[k]), bb.x), 0.f);
    float hy = fmaxf(fmaf(di, fmaf(di, fg.y, ay[k]), bb.y), 0.f);
    a1u[(size_t)r * 64 + lane] = pack2(hx, hy);
  }
}

// ---------------- weighted reduce: vpart[blk] = sum_r dinv[r]*(ssum[r]+dinv[r])*a1[r]
__global__ __launch_bounds__(256) void k_vred(const unsigned* __restrict__ a1u,
                                              const float* __restrict__ dinv,
                                              const float* __restrict__ ssum,
                                              float* __restrict__ vpart, int N) {
  int lane = threadIdx.x & 63;
  int wid = threadIdx.x >> 6;
  float vx = 0.f, vy = 0.f;
  for (int r = blockIdx.x * 4 + wid; r < N; r += gridDim.x * 4) {
    float di = dinv[r];
    float w = di * (ssum[r] + di);
    unsigned v = a1u[(size_t)r * 64 + lane];
    vx = fmaf(w, unpk_lo(v), vx);
    vy = fmaf(w, unpk_hi(v), vy);
  }
  __shared__ float2 red[256];
  red[threadIdx.x] = make_float2(vx, vy);
  __syncthreads();
  if (threadIdx.x < 64) {
    float2 a = red[threadIdx.x], b = red[threadIdx.x + 64];
    float2 c = red[threadIdx.x + 128], d = red[threadIdx.x + 192];
    float2 o = make_float2((a.x + b.x) + (c.x + d.x), (a.y + b.y) + (c.y + d.y));
    *(float2*)(vpart + (size_t)blockIdx.x * D + lane * 2) = o;
  }
}

// ---------------- final: v = sum partials; out = (1/N)*v@W2 + b2
__global__ __launch_bounds__(1024) void k_final(const float* __restrict__ vpart,
                                                int npart,
                                                const float* __restrict__ W2,
                                                const float* __restrict__ b2,
                                                float* __restrict__ out, float invN) {
  __shared__ float seg[8][128];
  __shared__ float vs[128];
  int t = threadIdx.x;
  int c = t & 127, sg = t >> 7;
  float s = 0.f;
  for (int b = sg; b < npart; b += 8) s += vpart[(size_t)b * D + c];
  seg[sg][c] = s;
  __syncthreads();
  if (t < 128) {
    float tot = 0.f;
    #pragma unroll
    for (int k = 0; k < 8; ++k) tot += seg[k][c];
    vs[c] = tot;
  }
  __syncthreads();
  if (t < 128) {
    float o = 0.f;
    for (int k = 0; k < 128; ++k) o = fmaf(vs[k], W2[k * D + c], o);
    out[c] = fmaf(o, invN, b2[c]);
  }
}

extern "C" void kernel_launch(void* const* d_in, const int* in_sizes, int n_in,
                              void* d_out, int out_size, void* d_ws, size_t ws_size,
                              hipStream_t stream) {
  const float* x  = (const float*)d_in[0];
  const int*   ei = (const int*)d_in[1];
  const float* W1 = (const float*)d_in[2];
  const float* b1 = (const float*)d_in[3];
  const float* W2 = (const float*)d_in[4];
  const float* b2 = (const float*)d_in[5];
  float* out = (float*)d_out;

  int N = in_sizes[0] / D;
  int E = in_sizes[1] / 2;
  const int* src = ei;
  const int* dst = ei + E;

  const int NBKT = (N + RPB - 1) / RPB;                    // 3125
  const int K2   = 2 * NBKT;                               // 6250 (both tables)
  const int ECH  = (((E + PB - 1) / PB) + 3) & ~3;         // 6252 (x4 aligned)
  const int TB   = (K2 + 255) / 256;                       // 25
  const int NGEMM = (N + 63) / 64;                         // 1563
  const int VRED_BLOCKS = 256;

  char* p = (char*)d_ws;
  float* ssum  = (float*)p;      p += (size_t)N * 4;
  float* dinv  = (float*)p;      p += (size_t)N * 4;
  int*   tot   = (int*)p;        p += 8192 * 4;
  int*   phT   = (int*)p;        p += (size_t)PB * K2 * 4;
  int*   eb    = (int*)p;        p += (size_t)(2 * E) * 4;
  p = (char*)(((uintptr_t)p + 255) & ~(uintptr_t)255);
  unsigned short* Wtg = (unsigned short*)p;  p += 128 * 128 * 2;
  p = (char*)(((uintptr_t)p + 255) & ~(uintptr_t)255);
  unsigned short* hu8 = (unsigned short*)p;  p += (size_t)N * 64 * 2;
  p = (char*)(((uintptr_t)p + 255) & ~(uintptr_t)255);
  unsigned* a1u = (unsigned*)p;  p += (size_t)N * 64 * 4;
  float* vpart  = (float*)p;

  k_hist<<<PB + 64, 256, 0, stream>>>(dst, src, phT, W1, Wtg, E, NBKT, ECH, K2);

  k_tots<<<TB, 256, 0, stream>>>(phT, tot, K2);

  k_scan3<<<TB, 256, 0, stream>>>(phT, tot, K2);

  k_scat_gemm<<<PB + NGEMM, 256, 0, stream>>>(src, dst, phT, eb, x, Wtg, hu8,
                                              N, E, NBKT, ECH, K2);

  k_rowdeg<<<NBKT, 256, 0, stream>>>(eb, phT, dinv, N, NBKT);

  k_bagg<<<2 * NBKT, 256, 0, stream>>>(hu8, eb, phT, dinv, ssum, b1, a1u,
                                       N, E, NBKT, K2);

  k_vred<<<VRED_BLOCKS, 256, 0, stream>>>(a1u, dinv, ssum, vpart, N);

  k_final<<<1, 1024, 0, stream>>>(vpart, VRED_BLOCKS, W2, b2, out, 1.0f / N);
}